// Round 7
// baseline (34.184 us; speedup 1.0000x reference)
//
#include <hip/hip_runtime.h>

#define HH 1024
#define WW 1024
#define NA 64
#define NBLK 1024
#define NGRP 32
#define GSIZE (NBLK / NGRP)   // 32 blocks per group

// ws control region: 65 cache lines of 128B (stride 32 ints):
//   wsi[0]             root counter
//   wsi[32*(1+g)]      group arrival counter g   (g < 32)
//   wsi[32*(33+g)]     flag g: 0 = not ready, else float bits of scale (>0)
// byte 8320..: float2 part[NBLK]
#define WS_CTRL_BYTES (128 * 65)

__global__ __launch_bounds__(256) void frp_one(
    const float4* __restrict__ field,
    const float4* __restrict__ signal,
    const int*   __restrict__ apos,       // [NA][2]
    const float* __restrict__ astr,       // [NA]
    const float* __restrict__ p_is,
    const float* __restrict__ p_gr,
    const float* __restrict__ p_lr,
    float4* __restrict__ out,
    unsigned* __restrict__ wsi,
    float2* __restrict__ part)
{
    __shared__ int    s_pj[NA];
    __shared__ int    s_rad[NA];
    __shared__ int    s_di2[NA];
    __shared__ float  s_coef[NA];
    __shared__ float  s_inv[NA];
    __shared__ int    s_nact;
    __shared__ float  s_partA[2][4];
    __shared__ double s_red[2][4];
    __shared__ int    s_last;
    __shared__ unsigned s_bits;

    const float lr = *p_lr;
    const float gr = *p_gr;
    const float is = *p_is;

    const int row = blockIdx.x;
    const int t   = threadIdx.x;
    const int g   = row >> 5;             // group index 0..31

    // ---- wave 0: compact row-active attractors (~1.1 of 64) ----
    if (t < NA) {
        float s  = astr[t];
        int   pi = apos[2 * t + 0];
        int   pj = apos[2 * t + 1];
        int   r  = (int)floorf(5.0f * s);
        int   di = row - pi;
        bool active = (di >= -r && di <= r);
        unsigned long long mask = __ballot(active);
        int pos = __popcll(mask & ((1ull << t) - 1ull));
        if (active) {
            s_pj[pos]   = pj;
            s_rad[pos]  = r;
            s_di2[pos]  = di * di;
            s_coef[pos] = lr * s;
            s_inv[pos]  = -0.125f / (s * s);
        }
        if (t == 0) s_nact = __popcll(mask);
    }
    __syncthreads();

    // ---- phase A: influence + blend, u kept in registers ----
    const int col0 = t << 2;
    const int n    = s_nact;

    float c0 = 0.f, c1 = 0.f, c2 = 0.f, c3 = 0.f;
    for (int k = 0; k < n; ++k) {
        int   pj  = s_pj[k];
        int   r   = s_rad[k];
        int   di2 = s_di2[k];
        float cf  = s_coef[k];
        float iv  = s_inv[k];
        int dj = col0 - pj;
        if (dj >= -r && dj <= r) c0 += cf * __expf(iv * (float)(di2 + dj * dj));
        int d1 = dj + 1;
        if (d1 >= -r && d1 <= r) c1 += cf * __expf(iv * (float)(di2 + d1 * d1));
        int d2 = dj + 2;
        if (d2 >= -r && d2 <= r) c2 += cf * __expf(iv * (float)(di2 + d2 * d2));
        int d3 = dj + 3;
        if (d3 >= -r && d3 <= r) c3 += cf * __expf(iv * (float)(di2 + d3 * d3));
    }

    const int idx = row * (WW / 4) + t;
    float4 f  = field[idx];
    float4 sg = signal[idx];

    float a0 = is / (1.0f + __expf(-(gr + c0)));
    float a1 = is / (1.0f + __expf(-(gr + c1)));
    float a2 = is / (1.0f + __expf(-(gr + c2)));
    float a3 = is / (1.0f + __expf(-(gr + c3)));

    float4 u;
    u.x = f.x + (sg.x - f.x) * a0;
    u.y = f.y + (sg.y - f.y) * a1;
    u.z = f.z + (sg.z - f.z) * a2;
    u.w = f.w + (sg.w - f.w) * a3;

    float sf = f.x * f.x + f.y * f.y + f.z * f.z + f.w * f.w;
    float su = u.x * u.x + u.y * u.y + u.z * u.z + u.w * u.w;
#pragma unroll
    for (int off = 32; off > 0; off >>= 1) {
        sf += __shfl_down(sf, off, 64);
        su += __shfl_down(su, off, 64);
    }
    const int wave = t >> 6;
    if ((t & 63) == 0) {
        s_partA[0][wave] = sf;
        s_partA[1][wave] = su;
    }
    __syncthreads();

    // ---- arrival: publish partial, 2-level counter tree ----
    if (t == 0) {
        part[row] = make_float2(
            s_partA[0][0] + s_partA[0][1] + s_partA[0][2] + s_partA[0][3],
            s_partA[1][0] + s_partA[1][1] + s_partA[1][2] + s_partA[1][3]);
        __threadfence();                                   // release partial
        unsigned old = atomicAdd(&wsi[32 * (1 + g)], 1u);  // group line
        int last = 0;
        if (old == GSIZE - 1) {                            // group leader
            __threadfence();
            unsigned o2 = atomicAdd(&wsi[0], 1u);          // root line
            if (o2 == NGRP - 1) last = 1;                  // final arrival
        }
        s_last = last;
    }
    __syncthreads();

    if (s_last) {
        // ---- reducer block: reduce 1024 partials, broadcast to 32 flags ----
        __threadfence();                                   // acquire
        double df = 0.0, du = 0.0;
#pragma unroll
        for (int k2 = 0; k2 < 4; ++k2) {
            unsigned long long pv = __hip_atomic_load(
                (const unsigned long long*)(part + t + 256 * k2),
                __ATOMIC_RELAXED, __HIP_MEMORY_SCOPE_AGENT);
            float2 p;
            __builtin_memcpy(&p, &pv, 8);
            df += (double)p.x;
            du += (double)p.y;
        }
#pragma unroll
        for (int off = 32; off > 0; off >>= 1) {
            df += __shfl_down(df, off, 64);
            du += __shfl_down(du, off, 64);
        }
        if ((t & 63) == 0) { s_red[0][wave] = df; s_red[1][wave] = du; }
        __syncthreads();
        if (t == 0) {
            double tf = s_red[0][0] + s_red[0][1] + s_red[0][2] + s_red[0][3];
            double tu = s_red[1][0] + s_red[1][1] + s_red[1][2] + s_red[1][3];
            float scale = (tu > 0.0) ? (float)sqrt(tf / tu) : 1.0f;
            s_bits = __float_as_uint(scale);
        }
        __syncthreads();
        if (t < NGRP)                                      // 32 flag lines
            __hip_atomic_store(&wsi[32 * (33 + t)], s_bits,
                               __ATOMIC_RELAXED, __HIP_MEMORY_SCOPE_AGENT);
    } else {
        // ---- poll own group's flag: relaxed agent loads + sleep ramp ----
        if (t == 0) {
            const unsigned* fl = &wsi[32 * (33 + g)];
            unsigned v = __hip_atomic_load(fl, __ATOMIC_RELAXED,
                                           __HIP_MEMORY_SCOPE_AGENT);
            if (v == 0u) {
                __builtin_amdgcn_s_sleep(8);
                v = __hip_atomic_load(fl, __ATOMIC_RELAXED, __HIP_MEMORY_SCOPE_AGENT);
            }
            if (v == 0u) {
                __builtin_amdgcn_s_sleep(16);
                v = __hip_atomic_load(fl, __ATOMIC_RELAXED, __HIP_MEMORY_SCOPE_AGENT);
            }
            if (v == 0u) {
                __builtin_amdgcn_s_sleep(32);
                v = __hip_atomic_load(fl, __ATOMIC_RELAXED, __HIP_MEMORY_SCOPE_AGENT);
            }
            while (v == 0u) {
                __builtin_amdgcn_s_sleep(64);
                v = __hip_atomic_load(fl, __ATOMIC_RELAXED, __HIP_MEMORY_SCOPE_AGENT);
            }
            s_bits = v;
        }
        __syncthreads();
    }

    const float sc = __uint_as_float(s_bits);
    u.x *= sc; u.y *= sc; u.z *= sc; u.w *= sc;
    out[idx] = u;
}

extern "C" void kernel_launch(void* const* d_in, const int* in_sizes, int n_in,
                              void* d_out, int out_size, void* d_ws, size_t ws_size,
                              hipStream_t stream) {
    const float4* field  = (const float4*)d_in[0];
    const float4* signal = (const float4*)d_in[1];
    const int*    apos   = (const int*)d_in[2];
    const float*  astr   = (const float*)d_in[3];
    const float*  p_is   = (const float*)d_in[4];
    const float*  p_gr   = (const float*)d_in[5];
    const float*  p_lr   = (const float*)d_in[6];

    unsigned* wsi  = (unsigned*)d_ws;
    float2*   part = (float2*)((char*)d_ws + WS_CTRL_BYTES);

    hipMemsetAsync(d_ws, 0, WS_CTRL_BYTES, stream);   // reset counters + flags

    frp_one<<<NBLK, 256, 0, stream>>>(
        field, signal, apos, astr, p_is, p_gr, p_lr,
        (float4*)d_out, wsi, part);
}

// Round 8
// 13.368 us; speedup vs baseline: 2.5571x; 2.5571x over previous
//
#include <hip/hip_runtime.h>

#define HH 1024
#define WW 1024
#define NA 64
#define NBLK1 512          // k1: 2 rows per block, 8 px per thread
#define NBLK2 512          // k2: 8 px per thread

// ws layout: float2 part[NBLK1]  (x = sum field^2, y = sum upd^2)

// ------------- Kernel 1: blend + unscaled out + norm partials --------------
__global__ __launch_bounds__(256) void frp_fused(
    const float4* __restrict__ field,
    const float4* __restrict__ signal,
    const int*   __restrict__ apos,       // [NA][2]
    const float* __restrict__ astr,       // [NA]
    const float* __restrict__ p_is,
    const float* __restrict__ p_gr,
    const float* __restrict__ p_lr,
    float4* __restrict__ out,
    float2* __restrict__ part)
{
    __shared__ int   s_pj[2][NA];
    __shared__ int   s_rad[2][NA];
    __shared__ int   s_di2[2][NA];
    __shared__ float s_coef[2][NA];
    __shared__ float s_inv[2][NA];
    __shared__ int   s_nact[2];
    __shared__ float s_part[2][4];

    const float lr = *p_lr;
    const float gr = *p_gr;
    const float is = *p_is;

    const int t    = threadIdx.x;
    const int row0 = blockIdx.x * 2;

    // ---- wave 0: compact active attractors for both rows ----
    if (t < NA) {
        float s  = astr[t];
        int   pi = apos[2 * t + 0];
        int   pj = apos[2 * t + 1];
        int   r  = (int)floorf(5.0f * s);
        float cf = lr * s;
        float iv = -0.125f / (s * s);
#pragma unroll
        for (int rr = 0; rr < 2; ++rr) {
            int di = (row0 + rr) - pi;
            bool active = (di >= -r && di <= r);
            unsigned long long mask = __ballot(active);
            int pos = __popcll(mask & ((1ull << t) - 1ull));
            if (active) {
                s_pj[rr][pos]   = pj;
                s_rad[rr][pos]  = r;
                s_di2[rr][pos]  = di * di;
                s_coef[rr][pos] = cf;
                s_inv[rr][pos]  = iv;
            }
            if (t == 0) s_nact[rr] = __popcll(mask);
        }
    }
    __syncthreads();

    // threads [0,128): row0, threads [128,256): row1  (wave-uniform)
    const int half = t >> 7;              // 0 or 1
    const int tt   = t & 127;             // position within row
    const int row  = row0 + half;
    const int col0 = tt << 3;             // 8 consecutive px
    const int n    = s_nact[half];

    float c[8] = {0,0,0,0,0,0,0,0};
    for (int k = 0; k < n; ++k) {         // ~1.1 iterations on average
        int   pj  = s_pj[half][k];
        int   r   = s_rad[half][k];
        int   di2 = s_di2[half][k];
        float cf  = s_coef[half][k];
        float iv  = s_inv[half][k];
#pragma unroll
        for (int q = 0; q < 8; ++q) {
            int dj = col0 + q - pj;
            if (dj >= -r && dj <= r)
                c[q] += cf * __expf(iv * (float)(di2 + dj * dj));
        }
    }

    const int idx = row * (WW / 4) + (tt << 1);
    float4 f0  = field[idx];
    float4 f1  = field[idx + 1];
    float4 g0  = signal[idx];
    float4 g1  = signal[idx + 1];

    float a[8];
#pragma unroll
    for (int q = 0; q < 8; ++q)
        a[q] = is / (1.0f + __expf(-(gr + c[q])));

    float4 u0, u1;
    u0.x = f0.x + (g0.x - f0.x) * a[0];
    u0.y = f0.y + (g0.y - f0.y) * a[1];
    u0.z = f0.z + (g0.z - f0.z) * a[2];
    u0.w = f0.w + (g0.w - f0.w) * a[3];
    u1.x = f1.x + (g1.x - f1.x) * a[4];
    u1.y = f1.y + (g1.y - f1.y) * a[5];
    u1.z = f1.z + (g1.z - f1.z) * a[6];
    u1.w = f1.w + (g1.w - f1.w) * a[7];
    out[idx]     = u0;
    out[idx + 1] = u1;

    float sf = f0.x*f0.x + f0.y*f0.y + f0.z*f0.z + f0.w*f0.w
             + f1.x*f1.x + f1.y*f1.y + f1.z*f1.z + f1.w*f1.w;
    float su = u0.x*u0.x + u0.y*u0.y + u0.z*u0.z + u0.w*u0.w
             + u1.x*u1.x + u1.y*u1.y + u1.z*u1.z + u1.w*u1.w;
#pragma unroll
    for (int off = 32; off > 0; off >>= 1) {
        sf += __shfl_down(sf, off, 64);
        su += __shfl_down(su, off, 64);
    }
    const int wave = t >> 6;
    if ((t & 63) == 0) {
        s_part[0][wave] = sf;
        s_part[1][wave] = su;
    }
    __syncthreads();
    if (t == 0) {
        part[blockIdx.x] = make_float2(
            s_part[0][0] + s_part[0][1] + s_part[0][2] + s_part[0][3],
            s_part[1][0] + s_part[1][1] + s_part[1][2] + s_part[1][3]);
    }
}

// ---- Kernel 2: reduce 512 partials (redundantly) and scale out in place ----
__global__ __launch_bounds__(256) void frp_scale(
    float4* __restrict__ out,
    const float2* __restrict__ part)
{
    __shared__ double sp[2][4];
    __shared__ float  s_scale;
    const int t = threadIdx.x;

    // 512 float2 = 256 float4: one per thread
    const float4* p4 = (const float4*)part;   // (f_{2k}, u_{2k}, f_{2k+1}, u_{2k+1})
    float4 v = p4[t];

    // issue out loads early (independent of the reduce)
    const int idx = blockIdx.x * 512 + (t << 1);  // 512 float4 per block
    float4 o0 = out[idx];
    float4 o1 = out[idx + 1];

    double df = (double)v.x + (double)v.z;
    double du = (double)v.y + (double)v.w;
#pragma unroll
    for (int off = 32; off > 0; off >>= 1) {
        df += __shfl_down(df, off, 64);
        du += __shfl_down(du, off, 64);
    }
    const int wave = t >> 6;
    if ((t & 63) == 0) { sp[0][wave] = df; sp[1][wave] = du; }
    __syncthreads();
    if (t == 0) {
        double tf = sp[0][0] + sp[0][1] + sp[0][2] + sp[0][3];
        double tu = sp[1][0] + sp[1][1] + sp[1][2] + sp[1][3];
        s_scale = (tu > 0.0) ? (float)sqrt(tf / tu) : 1.0f;
    }
    __syncthreads();

    const float s = s_scale;
    o0.x *= s; o0.y *= s; o0.z *= s; o0.w *= s;
    o1.x *= s; o1.y *= s; o1.z *= s; o1.w *= s;
    out[idx]     = o0;
    out[idx + 1] = o1;
}

extern "C" void kernel_launch(void* const* d_in, const int* in_sizes, int n_in,
                              void* d_out, int out_size, void* d_ws, size_t ws_size,
                              hipStream_t stream) {
    const float4* field  = (const float4*)d_in[0];
    const float4* signal = (const float4*)d_in[1];
    const int*    apos   = (const int*)d_in[2];
    const float*  astr   = (const float*)d_in[3];
    const float*  p_is   = (const float*)d_in[4];
    const float*  p_gr   = (const float*)d_in[5];
    const float*  p_lr   = (const float*)d_in[6];

    float2* part = (float2*)d_ws;

    frp_fused<<<NBLK1, 256, 0, stream>>>(
        field, signal, apos, astr, p_is, p_gr, p_lr,
        (float4*)d_out, part);

    frp_scale<<<NBLK2, 256, 0, stream>>>(
        (float4*)d_out, part);
}